// Round 1
// 517.072 us; speedup vs baseline: 1.0254x; 1.0254x over previous
//
#include <hip/hip_runtime.h>
#include <hip/hip_fp16.h>
#include <stdint.h>

#define NEG_ (-1e9f)

typedef _Float16 f16x8 __attribute__((ext_vector_type(8)));
typedef float    f32x4 __attribute__((ext_vector_type(4)));

__device__ __forceinline__ float fast_tanh(float x) {
  float e = __expf(2.0f * x);
  return (e - 1.0f) * __builtin_amdgcn_rcpf(e + 1.0f);
}

// ---------------------------------------------------------------------------
// K0: repack W [512 o][512 h] fp32 -> f16 in MFMA A-fragment stream order.
// seg = w*64 + ks*4 + io  (1KB each); w in 0..7 is the owning wave.
// lane i holds W[o = w*64+io*16+(i&15)][k = ks*32+(i>>4)*8 .. +8)
// ---------------------------------------------------------------------------
__global__ __launch_bounds__(256) void k0_cvt_w(const float* __restrict__ W,
                                                __half* __restrict__ Wws) {
  int g = blockIdx.x * 256 + threadIdx.x;   // 0..32767, one 16B chunk each
  int lane = g & 63;
  int seg  = g >> 6;                        // 0..511
  int io = seg & 3, ks = (seg >> 2) & 15, w = seg >> 6;   // w: 0..7
  int o = w * 64 + io * 16 + (lane & 15);
  int k = ks * 32 + (lane >> 4) * 8;
  const float2* src = (const float2*)(W + (size_t)o * 512 + k);
  __half2 h[4];
#pragma unroll
  for (int j = 0; j < 4; ++j) { float2 f = src[j]; h[j] = __floats2half2_rn(f.x, f.y); }
  uint4 u;
  u.x = *(uint32_t*)&h[0]; u.y = *(uint32_t*)&h[1];
  u.z = *(uint32_t*)&h[2]; u.w = *(uint32_t*)&h[3];
  *(uint4*)(Wws + (size_t)seg * 512 + (size_t)lane * 8) = u;
}

// ---------------------------------------------------------------------------
// K1: scores[m] = mask[m] ? v . tanh(W x_m + b) : -1e9 for 64 rows per block.
// X tile staged once to LDS (swizzled f16, ds_write_b128). 8 waves, each
// owning a 64-o x 64-s output tile; K = 16 stages of 32. A operand software-
// pipelined from L2 with depth-2 prefetch (3-slot register ring).
// 512 thr + 64KB LDS -> 2 blocks/CU = 16 waves/CU = 4 waves/SIMD.
// ---------------------------------------------------------------------------
__global__ __launch_bounds__(512, 4) void k1_scores(
    const float* __restrict__ enc, const int* __restrict__ msk,
    const float* __restrict__ bias, const float* __restrict__ ctx,
    const __half* __restrict__ Wws, float* __restrict__ scores) {
  __shared__ __align__(16) __half Xl[64 * 512];  // 64 KB

  const int t = threadIdx.x;
  const int w = t >> 6;          // 0..7: o-chunk this wave owns
  const int lane = t & 63;
  const int quad = lane >> 4;
  const int l15 = lane & 15;
  const size_t mtile = blockIdx.x;

  // ---- stage X tile [64 s][512 h] fp32 -> f16, XOR-swizzled 16B chunks ----
  {
    const float4* Xg = (const float4*)(enc + mtile * (size_t)(64 * 512));
#pragma unroll
    for (int j = 0; j < 8; ++j) {
      int g = j * 512 + t;        // f16 16B-chunk index 0..4095
      int s = g >> 6, c = g & 63;
      float4 x0 = Xg[s * 128 + 2 * c];
      float4 x1 = Xg[s * 128 + 2 * c + 1];
      __half2 h0 = __floats2half2_rn(x0.x, x0.y);
      __half2 h1 = __floats2half2_rn(x0.z, x0.w);
      __half2 h2 = __floats2half2_rn(x1.x, x1.y);
      __half2 h3 = __floats2half2_rn(x1.z, x1.w);
      uint4 u;
      u.x = *(uint32_t*)&h0; u.y = *(uint32_t*)&h1;
      u.z = *(uint32_t*)&h2; u.w = *(uint32_t*)&h3;
      int pc = c ^ (s & 7);     // phys chunk: bijective per wave -> conflict-free
      *(uint4*)&Xl[s * 512 + pc * 8] = u;
    }
  }
  __syncthreads();

  // A-fragment register ring, depth-2 prefetch from L2-resident Wws
  f16x8 abuf[3][4];
  auto aload = [&](int slot, int ks) {
    const f16x8* sp = (const f16x8*)(Wws +
        ((size_t)(w * 64 + ks * 4) * 512) + (size_t)lane * 8);
#pragma unroll
    for (int io = 0; io < 4; ++io) abuf[slot][io] = sp[io * 64];
  };
  aload(0, 0);
  aload(1, 1);

  f32x4 acc[4][4];
#pragma unroll
  for (int io = 0; io < 4; ++io)
#pragma unroll
    for (int is = 0; is < 4; ++is) acc[io][is] = (f32x4){0.f, 0.f, 0.f, 0.f};

#pragma unroll
  for (int ks = 0; ks < 16; ++ks) {
    if (ks + 2 < 16) aload((ks + 2) % 3, ks + 2);  // prefetch ahead
    const f16x8* acur = abuf[ks % 3];
#pragma unroll
    for (int is = 0; is < 4; ++is) {
      int s = is * 16 + l15;
      const f16x8 bf = *(const f16x8*)&Xl[s * 512 + (((ks * 4 + quad) ^ (s & 7)) << 3)];
#pragma unroll
      for (int io = 0; io < 4; ++io)
        acc[io][is] = __builtin_amdgcn_mfma_f32_16x16x32_f16(acur[io], bf, acc[io][is], 0, 0, 0);
    }
  }

  // epilogue: fold tanh(acc + b) * v into per-row partial scores
  float ps[4] = {0.f, 0.f, 0.f, 0.f};
#pragma unroll
  for (int io = 0; io < 4; ++io) {
    int ob = w * 64 + io * 16 + quad * 4;   // C row m = quad*4 + reg
    float4 b4 = *(const float4*)(bias + ob);
    float4 v4 = *(const float4*)(ctx + ob);
#pragma unroll
    for (int is = 0; is < 4; ++is) {
      const f32x4 a = acc[io][is];
      ps[is] += fast_tanh(a[0] + b4.x) * v4.x + fast_tanh(a[1] + b4.y) * v4.y +
                fast_tanh(a[2] + b4.z) * v4.z + fast_tanh(a[3] + b4.w) * v4.w;
    }
  }
#pragma unroll
  for (int is = 0; is < 4; ++is) {   // sum over this wave's 64 o's
    ps[is] += __shfl_xor(ps[is], 16, 64);
    ps[is] += __shfl_xor(ps[is], 32, 64);
  }

  // cross-wave reduction (X tile is dead now -> reuse its LDS)
  __syncthreads();
  float* sred = (float*)&Xl[0];
  if (lane < 16) {
#pragma unroll
    for (int is = 0; is < 4; ++is) sred[w * 64 + is * 16 + lane] = ps[is];
  }
  __syncthreads();
  if (t < 64) {
    float sc = 0.f;
#pragma unroll
    for (int k = 0; k < 8; ++k) sc += sred[k * 64 + t];
    size_t row = mtile * 64 + t;
    scores[row] = msk[row] ? sc : NEG_;
  }
}

// ---------------------------------------------------------------------------
// K2: in-place masked softmax over S=2048 per batch row (scores -> attn)
// ---------------------------------------------------------------------------
__global__ __launch_bounds__(256) void k2_softmax(float* __restrict__ attn) {
  const int b = blockIdx.x, t = threadIdx.x;
  float* row = attn + (size_t)b * 2048;
  float v[8];
  float mx = -3.4e38f;
#pragma unroll
  for (int i = 0; i < 8; ++i) { v[i] = row[t + 256 * i]; mx = fmaxf(mx, v[i]); }
#pragma unroll
  for (int off = 32; off >= 1; off >>= 1) mx = fmaxf(mx, __shfl_xor(mx, off, 64));
  __shared__ float r1[4], r2[4];
  int w = t >> 6, lane = t & 63;
  if (lane == 0) r1[w] = mx;
  __syncthreads();
  mx = fmaxf(fmaxf(r1[0], r1[1]), fmaxf(r1[2], r1[3]));
  float sum = 0.f;
#pragma unroll
  for (int i = 0; i < 8; ++i) { v[i] = __expf(v[i] - mx); sum += v[i]; }
#pragma unroll
  for (int off = 32; off >= 1; off >>= 1) sum += __shfl_xor(sum, off, 64);
  if (lane == 0) r2[w] = sum;
  __syncthreads();
  sum = r2[0] + r2[1] + r2[2] + r2[3];
  float inv = 1.0f / sum;
#pragma unroll
  for (int i = 0; i < 8; ++i) row[t + 256 * i] = v[i] * inv;
}

// ---------------------------------------------------------------------------
// K3: out[b,h] = sum_s attn[b,s] * x[b,s,h].  2048 blocks (b x 32 s-chunks of
// 64 rows), 8 blocks/CU, float4 streams. The two row-parity partials are
// folded through LDS first, then ONE fp32 atomic per output float (halves
// atomic count vs previous version).
// ---------------------------------------------------------------------------
__global__ __launch_bounds__(256) void k3_wsum(const float* __restrict__ enc,
                                               const float* __restrict__ attn,
                                               float* __restrict__ out0) {
  const int bb = blockIdx.x >> 5, sc = blockIdx.x & 31, t = threadIdx.x;
  const int r = t >> 7;        // 0/1: which row parity this thread covers
  const int c = t & 127;       // float4 column
  __shared__ float a_s[64];
  __shared__ __align__(16) float4 part[128];
  if (t < 64) a_s[t] = attn[(size_t)bb * 2048 + sc * 64 + t];
  __syncthreads();
  const float4* Xg = (const float4*)(enc + ((size_t)bb * 2048 + (size_t)sc * 64) * 512);
  float4 acc = {0.f, 0.f, 0.f, 0.f};
#pragma unroll 8
  for (int s = r; s < 64; s += 2) {
    float a = a_s[s];
    float4 x = Xg[(size_t)s * 128 + c];
    acc.x = fmaf(a, x.x, acc.x);
    acc.y = fmaf(a, x.y, acc.y);
    acc.z = fmaf(a, x.z, acc.z);
    acc.w = fmaf(a, x.w, acc.w);
  }
  if (r) part[c] = acc;
  __syncthreads();
  if (!r) {
    float4 o = part[c];
    float* op = out0 + (size_t)bb * 512 + c * 4;
    atomicAdd(op + 0, acc.x + o.x);
    atomicAdd(op + 1, acc.y + o.y);
    atomicAdd(op + 2, acc.z + o.z);
    atomicAdd(op + 3, acc.w + o.w);
  }
}

// ---------------------------------------------------------------------------
extern "C" void kernel_launch(void* const* d_in, const int* in_sizes, int n_in,
                              void* d_out, int out_size, void* d_ws, size_t ws_size,
                              hipStream_t stream) {
  (void)in_sizes; (void)n_in; (void)out_size; (void)ws_size;
  const float* enc  = (const float*)d_in[0];  // [64,2048,512] fp32
  const int*   msk  = (const int*)d_in[1];    // [64,2048] bool->int32
  const float* W    = (const float*)d_in[2];  // [512,512] fp32
  const float* bias = (const float*)d_in[3];  // [512] fp32
  const float* ctx  = (const float*)d_in[4];  // [512] fp32
  float* out0 = (float*)d_out;                // [64,512] weighted output
  float* attn = out0 + 64 * 512;              // [64,2048] scores -> attn (in place)
  __half* Wws = (__half*)d_ws;                // 512 KB repacked W

  hipMemsetAsync(out0, 0, 64 * 512 * sizeof(float), stream);
  k0_cvt_w<<<128, 256, 0, stream>>>(W, Wws);
  k1_scores<<<2048, 512, 0, stream>>>(enc, msk, bias, ctx, Wws, attn);
  k2_softmax<<<64, 256, 0, stream>>>(attn);
  k3_wsum<<<2048, 256, 0, stream>>>(enc, attn, out0);
}

// Round 2
// 510.962 us; speedup vs baseline: 1.0376x; 1.0120x over previous
//
#include <hip/hip_runtime.h>
#include <hip/hip_fp16.h>
#include <stdint.h>

#define NEG_ (-1e9f)

typedef _Float16 f16x8 __attribute__((ext_vector_type(8)));
typedef float    f32x4 __attribute__((ext_vector_type(4)));

__device__ __forceinline__ float fast_tanh(float x) {
  float e = __expf(2.0f * x);
  return (e - 1.0f) * __builtin_amdgcn_rcpf(e + 1.0f);
}

// ---------------------------------------------------------------------------
// K0: repack W [512 o][512 h] fp32 -> f16 in MFMA A-fragment stream order.
// seg = w*64 + ks*4 + io  (1KB each); w in 0..7 is the owning wave.
// lane i holds W[o = w*64+io*16+(i&15)][k = ks*32+(i>>4)*8 .. +8)
// ---------------------------------------------------------------------------
__global__ __launch_bounds__(256) void k0_cvt_w(const float* __restrict__ W,
                                                __half* __restrict__ Wws) {
  int g = blockIdx.x * 256 + threadIdx.x;   // 0..32767, one 16B chunk each
  int lane = g & 63;
  int seg  = g >> 6;                        // 0..511
  int io = seg & 3, ks = (seg >> 2) & 15, w = seg >> 6;   // w: 0..7
  int o = w * 64 + io * 16 + (lane & 15);
  int k = ks * 32 + (lane >> 4) * 8;
  const float2* src = (const float2*)(W + (size_t)o * 512 + k);
  __half2 h[4];
#pragma unroll
  for (int j = 0; j < 4; ++j) { float2 f = src[j]; h[j] = __floats2half2_rn(f.x, f.y); }
  uint4 u;
  u.x = *(uint32_t*)&h[0]; u.y = *(uint32_t*)&h[1];
  u.z = *(uint32_t*)&h[2]; u.w = *(uint32_t*)&h[3];
  *(uint4*)(Wws + (size_t)seg * 512 + (size_t)lane * 8) = u;
}

// ---------------------------------------------------------------------------
// K1 (fused): per 64-row chunk mtile:
//   scores[m] = mask ? v.tanh(W x_m + b) : -1e9      (written raw for combine)
//   m_c = max_m scores, l_c = sum e^(s-m_c)
//   psum_c[h] = sum_m e^(s_m - m_c) * x[m,h]   -- read from the resident LDS
//   X tile (f16), eliminating k3's 256 MB enc re-read and all atomics.
// 8 waves; LDS 66.3 KB -> still 2 blocks/CU (gfx950 LDS = 160 KB/CU).
// ---------------------------------------------------------------------------
__global__ __launch_bounds__(512, 4) void k1_scores(
    const float* __restrict__ enc, const int* __restrict__ msk,
    const float* __restrict__ bias, const float* __restrict__ ctx,
    const __half* __restrict__ Wws, float* __restrict__ scores,
    float* __restrict__ psum, float* __restrict__ mpart,
    float* __restrict__ lpart) {
  __shared__ __align__(16) __half Xl[64 * 512];  // 64 KB
  __shared__ float sred[512];
  __shared__ float pbuf[64];

  const int t = threadIdx.x;
  const int w = t >> 6;          // 0..7: o-chunk this wave owns
  const int lane = t & 63;
  const int quad = lane >> 4;
  const int l15 = lane & 15;
  const size_t mtile = blockIdx.x;

  // ---- stage X tile [64 s][512 h] fp32 -> f16, XOR-swizzled 16B chunks ----
  {
    const float4* Xg = (const float4*)(enc + mtile * (size_t)(64 * 512));
#pragma unroll
    for (int j = 0; j < 8; ++j) {
      int g = j * 512 + t;        // f16 16B-chunk index 0..4095
      int s = g >> 6, c = g & 63;
      float4 x0 = Xg[s * 128 + 2 * c];
      float4 x1 = Xg[s * 128 + 2 * c + 1];
      __half2 h0 = __floats2half2_rn(x0.x, x0.y);
      __half2 h1 = __floats2half2_rn(x0.z, x0.w);
      __half2 h2 = __floats2half2_rn(x1.x, x1.y);
      __half2 h3 = __floats2half2_rn(x1.z, x1.w);
      uint4 u;
      u.x = *(uint32_t*)&h0; u.y = *(uint32_t*)&h1;
      u.z = *(uint32_t*)&h2; u.w = *(uint32_t*)&h3;
      int pc = c ^ (s & 7);     // phys chunk: bijective per wave -> conflict-free
      *(uint4*)&Xl[s * 512 + pc * 8] = u;
    }
  }
  __syncthreads();

  // A-fragment register ring, depth-2 prefetch from L2-resident Wws
  f16x8 abuf[3][4];
  auto aload = [&](int slot, int ks) {
    const f16x8* sp = (const f16x8*)(Wws +
        ((size_t)(w * 64 + ks * 4) * 512) + (size_t)lane * 8);
#pragma unroll
    for (int io = 0; io < 4; ++io) abuf[slot][io] = sp[io * 64];
  };
  aload(0, 0);
  aload(1, 1);

  f32x4 acc[4][4];
#pragma unroll
  for (int io = 0; io < 4; ++io)
#pragma unroll
    for (int is = 0; is < 4; ++is) acc[io][is] = (f32x4){0.f, 0.f, 0.f, 0.f};

#pragma unroll
  for (int ks = 0; ks < 16; ++ks) {
    if (ks + 2 < 16) aload((ks + 2) % 3, ks + 2);  // prefetch ahead
    const f16x8* acur = abuf[ks % 3];
#pragma unroll
    for (int is = 0; is < 4; ++is) {
      int s = is * 16 + l15;
      const f16x8 bf = *(const f16x8*)&Xl[s * 512 + (((ks * 4 + quad) ^ (s & 7)) << 3)];
#pragma unroll
      for (int io = 0; io < 4; ++io)
        acc[io][is] = __builtin_amdgcn_mfma_f32_16x16x32_f16(acur[io], bf, acc[io][is], 0, 0, 0);
    }
  }

  // epilogue: fold tanh(acc + b) * v into per-row partial scores
  float ps[4] = {0.f, 0.f, 0.f, 0.f};
#pragma unroll
  for (int io = 0; io < 4; ++io) {
    int ob = w * 64 + io * 16 + quad * 4;   // C row m = quad*4 + reg
    float4 b4 = *(const float4*)(bias + ob);
    float4 v4 = *(const float4*)(ctx + ob);
#pragma unroll
    for (int is = 0; is < 4; ++is) {
      const f32x4 a = acc[io][is];
      ps[is] += fast_tanh(a[0] + b4.x) * v4.x + fast_tanh(a[1] + b4.y) * v4.y +
                fast_tanh(a[2] + b4.z) * v4.z + fast_tanh(a[3] + b4.w) * v4.w;
    }
  }
#pragma unroll
  for (int is = 0; is < 4; ++is) {   // sum over this wave's 64 o's
    ps[is] += __shfl_xor(ps[is], 16, 64);
    ps[is] += __shfl_xor(ps[is], 32, 64);
  }

  // cross-wave score reduction (X tile must STAY alive -> separate sred)
  __syncthreads();
  if (lane < 16) {
#pragma unroll
    for (int is = 0; is < 4; ++is) sred[w * 64 + is * 16 + lane] = ps[is];
  }
  __syncthreads();
  if (t < 64) {   // wave 0: finalize scores + local softmax stats
    float sc = 0.f;
#pragma unroll
    for (int k = 0; k < 8; ++k) sc += sred[k * 64 + t];
    size_t row = mtile * 64 + t;
    float sm = msk[row] ? sc : NEG_;
    scores[row] = sm;                       // raw masked score for combine pass
    float m = sm;
#pragma unroll
    for (int off = 32; off >= 1; off >>= 1) m = fmaxf(m, __shfl_xor(m, off, 64));
    float p = __expf(sm - m);
    float l = p;
#pragma unroll
    for (int off = 32; off >= 1; off >>= 1) l += __shfl_xor(l, off, 64);
    pbuf[t] = p;
    if (t == 0) { mpart[mtile] = m; lpart[mtile] = l; }
  }
  __syncthreads();

  // partial weighted sum from the resident LDS X tile:
  // wave w covers s = w*8..w*8+7; lane c covers h = c*8..c*8+7
  float pacc[8] = {0.f, 0.f, 0.f, 0.f, 0.f, 0.f, 0.f, 0.f};
  const int c = lane;
#pragma unroll
  for (int si = 0; si < 8; ++si) {
    int s = (w << 3) + si;
    float pv = pbuf[s];
    f16x8 xv = *(const f16x8*)&Xl[s * 512 + ((c ^ (s & 7)) << 3)];
#pragma unroll
    for (int j = 0; j < 8; ++j) pacc[j] = fmaf(pv, (float)xv[j], pacc[j]);
  }
  __syncthreads();                  // all reads of Xl done -> reuse as pred
  float* pred = (float*)&Xl[0];     // layout [w][half][c][4]
  {
    float4 lo = {pacc[0], pacc[1], pacc[2], pacc[3]};
    float4 hi = {pacc[4], pacc[5], pacc[6], pacc[7]};
    *(float4*)&pred[w * 512 + c * 4] = lo;          // conflict-free b128 stores
    *(float4*)&pred[w * 512 + 256 + c * 4] = hi;
  }
  __syncthreads();
  if (t < 128) {                    // h float4-group g = t
    int half = t & 1, c2 = t >> 1;
    float4 a = {0.f, 0.f, 0.f, 0.f};
#pragma unroll
    for (int w2 = 0; w2 < 8; ++w2) {
      float4 pv = *(const float4*)&pred[w2 * 512 + half * 256 + c2 * 4];
      a.x += pv.x; a.y += pv.y; a.z += pv.z; a.w += pv.w;
    }
    *(float4*)&psum[mtile * 512 + (size_t)t * 4] = a;
  }
}

// ---------------------------------------------------------------------------
// K2 (combine): per batch b, reduce 32 chunk partials:
//   M = max m_c; Z = sum l_c e^(m_c-M)
//   attn[b,s] = e^(score - M)/Z  (exact softmax, in place)
//   out[b,h]  = sum_c e^(m_c-M) * psum_c[h] / Z
// ---------------------------------------------------------------------------
__global__ __launch_bounds__(256) void k2_combine(
    float* __restrict__ attn, const float* __restrict__ psum,
    const float* __restrict__ mpart, const float* __restrict__ lpart,
    float* __restrict__ out0) {
  const int b = blockIdx.x, t = threadIdx.x;
  __shared__ float ml[32], ll[32];
  if (t < 32) { ml[t] = mpart[b * 32 + t]; ll[t] = lpart[b * 32 + t]; }
  __syncthreads();
  float M = -3.4e38f;
#pragma unroll
  for (int i = 0; i < 32; ++i) M = fmaxf(M, ml[i]);
  float wgt[32];
  float Z = 0.f;
#pragma unroll
  for (int i = 0; i < 32; ++i) {
    float e = __expf(ml[i] - M);
    wgt[i] = e;
    Z += e * ll[i];
  }
  float invZ = 1.0f / Z;
  float* row = attn + (size_t)b * 2048;
#pragma unroll
  for (int i = 0; i < 8; ++i) {
    int s = t + 256 * i;
    row[s] = __expf(row[s] - M) * invZ;
  }
  if (t < 128) {
    float4 a = {0.f, 0.f, 0.f, 0.f};
#pragma unroll
    for (int c2 = 0; c2 < 32; ++c2) {
      float wv = wgt[c2];
      float4 p = *(const float4*)&psum[((size_t)(b * 32 + c2)) * 512 + (size_t)t * 4];
      a.x = fmaf(wv, p.x, a.x);
      a.y = fmaf(wv, p.y, a.y);
      a.z = fmaf(wv, p.z, a.z);
      a.w = fmaf(wv, p.w, a.w);
    }
    float4 r = {a.x * invZ, a.y * invZ, a.z * invZ, a.w * invZ};
    *(float4*)&out0[(size_t)b * 512 + (size_t)t * 4] = r;
  }
}

// ---------------------------------------------------------------------------
extern "C" void kernel_launch(void* const* d_in, const int* in_sizes, int n_in,
                              void* d_out, int out_size, void* d_ws, size_t ws_size,
                              hipStream_t stream) {
  (void)in_sizes; (void)n_in; (void)out_size; (void)ws_size;
  const float* enc  = (const float*)d_in[0];  // [64,2048,512] fp32
  const int*   msk  = (const int*)d_in[1];    // [64,2048] bool->int32
  const float* W    = (const float*)d_in[2];  // [512,512] fp32
  const float* bias = (const float*)d_in[3];  // [512] fp32
  const float* ctx  = (const float*)d_in[4];  // [512] fp32
  float* out0 = (float*)d_out;                // [64,512] weighted output
  float* attn = out0 + 64 * 512;              // [64,2048] scores -> attn (in place)

  __half* Wws  = (__half*)d_ws;                               // 512 KB
  float*  psum = (float*)((char*)d_ws + (512u << 10));        // 4 MB  [2048][512]
  float*  mprt = psum + (size_t)2048 * 512;                   // 8 KB
  float*  lprt = mprt + 2048;                                 // 8 KB

  k0_cvt_w<<<128, 256, 0, stream>>>(W, Wws);
  k1_scores<<<2048, 512, 0, stream>>>(enc, msk, bias, ctx, Wws, attn,
                                      psum, mprt, lprt);
  k2_combine<<<64, 256, 0, stream>>>(attn, psum, mprt, lprt, out0);
}

// Round 3
// 444.413 us; speedup vs baseline: 1.1930x; 1.1497x over previous
//
#include <hip/hip_runtime.h>
#include <hip/hip_fp16.h>
#include <stdint.h>

#define NEG_ (-1e9f)

typedef _Float16 f16x8 __attribute__((ext_vector_type(8)));
typedef float    f32x4 __attribute__((ext_vector_type(4)));

__device__ __forceinline__ float fast_tanh(float x) {
  float e = __expf(2.0f * x);
  return (e - 1.0f) * __builtin_amdgcn_rcpf(e + 1.0f);
}

// ---------------------------------------------------------------------------
// K0: repack W [512 o][512 h] fp32 -> f16 in MFMA A-fragment stream order.
// seg = w*64 + ks*4 + io  (1KB each); w in 0..7 is the owning wave.
// lane i holds W[o = w*64+io*16+(i&15)][k = ks*32+(i>>4)*8 .. +8)
// ---------------------------------------------------------------------------
__global__ __launch_bounds__(256) void k0_cvt_w(const float* __restrict__ W,
                                                __half* __restrict__ Wws) {
  int g = blockIdx.x * 256 + threadIdx.x;   // 0..32767, one 16B chunk each
  int lane = g & 63;
  int seg  = g >> 6;                        // 0..511
  int io = seg & 3, ks = (seg >> 2) & 15, w = seg >> 6;   // w: 0..7
  int o = w * 64 + io * 16 + (lane & 15);
  int k = ks * 32 + (lane >> 4) * 8;
  const float2* src = (const float2*)(W + (size_t)o * 512 + k);
  __half2 h[4];
#pragma unroll
  for (int j = 0; j < 4; ++j) { float2 f = src[j]; h[j] = __floats2half2_rn(f.x, f.y); }
  uint4 u;
  u.x = *(uint32_t*)&h[0]; u.y = *(uint32_t*)&h[1];
  u.z = *(uint32_t*)&h[2]; u.w = *(uint32_t*)&h[3];
  *(uint4*)(Wws + (size_t)seg * 512 + (size_t)lane * 8) = u;
}

// ---------------------------------------------------------------------------
// K1 (fused): per 64-row chunk mtile:
//   scores[m] = mask ? v.tanh(W x_m + b) : -1e9      (written raw for combine)
//   m_c = max_m scores, l_c = sum e^(s-m_c)
//   psum_c[h] = sum_m e^(s_m - m_c) * x[m,h]   -- from the resident LDS tile.
// Staging is two-phase: ALL 16 float4 global loads issued into a register
// array first (full memory-level parallelism; the old fused loop had ~2
// loads in flight per thread and ran at HBM latency, not HBM bandwidth),
// then fp32->f16 convert + swizzled ds_write_b128. W-fragment prefetch
// issued between the phases so its L2 latency hides under conversion.
// ---------------------------------------------------------------------------
__global__ __launch_bounds__(512, 4) void k1_scores(
    const float* __restrict__ enc, const int* __restrict__ msk,
    const float* __restrict__ bias, const float* __restrict__ ctx,
    const __half* __restrict__ Wws, float* __restrict__ scores,
    float* __restrict__ psum, float* __restrict__ mpart,
    float* __restrict__ lpart) {
  __shared__ __align__(16) __half Xl[64 * 512];  // 64 KB
  __shared__ float sred[512];
  __shared__ float pbuf[64];

  const int t = threadIdx.x;
  const int w = t >> 6;          // 0..7: o-chunk this wave owns
  const int lane = t & 63;
  const int quad = lane >> 4;
  const int l15 = lane & 15;
  const size_t mtile = blockIdx.x;

  // A-fragment register ring, depth-2 prefetch from L2-resident Wws
  f16x8 abuf[3][4];
  auto aload = [&](int slot, int ks) {
    const f16x8* sp = (const f16x8*)(Wws +
        ((size_t)(w * 64 + ks * 4) * 512) + (size_t)lane * 8);
#pragma unroll
    for (int io = 0; io < 4; ++io) abuf[slot][io] = sp[io * 64];
  };

  // ---- stage X tile [64 s][512 h] fp32 -> f16, XOR-swizzled 16B chunks ----
  {
    const float4* Xg = (const float4*)(enc + mtile * (size_t)(64 * 512));
    float4 xr[16];
    // phase 1: issue every global load (independent addresses -> 16 in flight)
#pragma unroll
    for (int j = 0; j < 8; ++j) {
      int g = j * 512 + t;        // f16 16B-chunk index 0..4095
      int s = g >> 6, c = g & 63;
      xr[2 * j]     = Xg[s * 128 + 2 * c];
      xr[2 * j + 1] = Xg[s * 128 + 2 * c + 1];
    }
    // W prefetch issued now: L2 latency overlaps the conversion phase below
    aload(0, 0);
    aload(1, 1);
    // phase 2: convert + swizzled LDS store (waits drain vmcnt incrementally)
#pragma unroll
    for (int j = 0; j < 8; ++j) {
      int g = j * 512 + t;
      int s = g >> 6, c = g & 63;
      float4 x0 = xr[2 * j];
      float4 x1 = xr[2 * j + 1];
      __half2 h0 = __floats2half2_rn(x0.x, x0.y);
      __half2 h1 = __floats2half2_rn(x0.z, x0.w);
      __half2 h2 = __floats2half2_rn(x1.x, x1.y);
      __half2 h3 = __floats2half2_rn(x1.z, x1.w);
      uint4 u;
      u.x = *(uint32_t*)&h0; u.y = *(uint32_t*)&h1;
      u.z = *(uint32_t*)&h2; u.w = *(uint32_t*)&h3;
      int pc = c ^ (s & 7);     // phys chunk: bijective per wave -> conflict-free
      *(uint4*)&Xl[s * 512 + pc * 8] = u;
    }
  }
  __syncthreads();

  f32x4 acc[4][4];
#pragma unroll
  for (int io = 0; io < 4; ++io)
#pragma unroll
    for (int is = 0; is < 4; ++is) acc[io][is] = (f32x4){0.f, 0.f, 0.f, 0.f};

#pragma unroll
  for (int ks = 0; ks < 16; ++ks) {
    if (ks + 2 < 16) aload((ks + 2) % 3, ks + 2);  // prefetch ahead
    const f16x8* acur = abuf[ks % 3];
#pragma unroll
    for (int is = 0; is < 4; ++is) {
      int s = is * 16 + l15;
      const f16x8 bf = *(const f16x8*)&Xl[s * 512 + (((ks * 4 + quad) ^ (s & 7)) << 3)];
#pragma unroll
      for (int io = 0; io < 4; ++io)
        acc[io][is] = __builtin_amdgcn_mfma_f32_16x16x32_f16(acur[io], bf, acc[io][is], 0, 0, 0);
    }
  }

  // epilogue: fold tanh(acc + b) * v into per-row partial scores
  float ps[4] = {0.f, 0.f, 0.f, 0.f};
#pragma unroll
  for (int io = 0; io < 4; ++io) {
    int ob = w * 64 + io * 16 + quad * 4;   // C row m = quad*4 + reg
    float4 b4 = *(const float4*)(bias + ob);
    float4 v4 = *(const float4*)(ctx + ob);
#pragma unroll
    for (int is = 0; is < 4; ++is) {
      const f32x4 a = acc[io][is];
      ps[is] += fast_tanh(a[0] + b4.x) * v4.x + fast_tanh(a[1] + b4.y) * v4.y +
                fast_tanh(a[2] + b4.z) * v4.z + fast_tanh(a[3] + b4.w) * v4.w;
    }
  }
#pragma unroll
  for (int is = 0; is < 4; ++is) {   // sum over this wave's 64 o's
    ps[is] += __shfl_xor(ps[is], 16, 64);
    ps[is] += __shfl_xor(ps[is], 32, 64);
  }

  // cross-wave score reduction (X tile must STAY alive -> separate sred)
  __syncthreads();
  if (lane < 16) {
#pragma unroll
    for (int is = 0; is < 4; ++is) sred[w * 64 + is * 16 + lane] = ps[is];
  }
  __syncthreads();
  if (t < 64) {   // wave 0: finalize scores + local softmax stats
    float sc = 0.f;
#pragma unroll
    for (int k = 0; k < 8; ++k) sc += sred[k * 64 + t];
    size_t row = mtile * 64 + t;
    float sm = msk[row] ? sc : NEG_;
    scores[row] = sm;                       // raw masked score for combine pass
    float m = sm;
#pragma unroll
    for (int off = 32; off >= 1; off >>= 1) m = fmaxf(m, __shfl_xor(m, off, 64));
    float p = __expf(sm - m);
    float l = p;
#pragma unroll
    for (int off = 32; off >= 1; off >>= 1) l += __shfl_xor(l, off, 64);
    pbuf[t] = p;
    if (t == 0) { mpart[mtile] = m; lpart[mtile] = l; }
  }
  __syncthreads();

  // partial weighted sum from the resident LDS X tile:
  // wave w covers s = w*8..w*8+7; lane c covers h = c*8..c*8+7
  float pacc[8] = {0.f, 0.f, 0.f, 0.f, 0.f, 0.f, 0.f, 0.f};
  const int c = lane;
#pragma unroll
  for (int si = 0; si < 8; ++si) {
    int s = (w << 3) + si;
    float pv = pbuf[s];
    f16x8 xv = *(const f16x8*)&Xl[s * 512 + ((c ^ (s & 7)) << 3)];
#pragma unroll
    for (int j = 0; j < 8; ++j) pacc[j] = fmaf(pv, (float)xv[j], pacc[j]);
  }
  __syncthreads();                  // all reads of Xl done -> reuse as pred
  float* pred = (float*)&Xl[0];     // layout [w][half][c][4]
  {
    float4 lo = {pacc[0], pacc[1], pacc[2], pacc[3]};
    float4 hi = {pacc[4], pacc[5], pacc[6], pacc[7]};
    *(float4*)&pred[w * 512 + c * 4] = lo;          // conflict-free b128 stores
    *(float4*)&pred[w * 512 + 256 + c * 4] = hi;
  }
  __syncthreads();
  if (t < 128) {                    // h float4-group g = t
    int half = t & 1, c2 = t >> 1;
    float4 a = {0.f, 0.f, 0.f, 0.f};
#pragma unroll
    for (int w2 = 0; w2 < 8; ++w2) {
      float4 pv = *(const float4*)&pred[w2 * 512 + half * 256 + c2 * 4];
      a.x += pv.x; a.y += pv.y; a.z += pv.z; a.w += pv.w;
    }
    *(float4*)&psum[mtile * 512 + (size_t)t * 4] = a;
  }
}

// ---------------------------------------------------------------------------
// K2 (combine): per batch b, reduce 32 chunk partials:
//   M = max m_c; Z = sum l_c e^(m_c-M)
//   attn[b,s] = e^(score - M)/Z  (exact softmax, in place)
//   out[b,h]  = sum_c e^(m_c-M) * psum_c[h] / Z
// ---------------------------------------------------------------------------
__global__ __launch_bounds__(256) void k2_combine(
    float* __restrict__ attn, const float* __restrict__ psum,
    const float* __restrict__ mpart, const float* __restrict__ lpart,
    float* __restrict__ out0) {
  const int b = blockIdx.x, t = threadIdx.x;
  __shared__ float ml[32], ll[32];
  if (t < 32) { ml[t] = mpart[b * 32 + t]; ll[t] = lpart[b * 32 + t]; }
  __syncthreads();
  float M = -3.4e38f;
#pragma unroll
  for (int i = 0; i < 32; ++i) M = fmaxf(M, ml[i]);
  float wgt[32];
  float Z = 0.f;
#pragma unroll
  for (int i = 0; i < 32; ++i) {
    float e = __expf(ml[i] - M);
    wgt[i] = e;
    Z += e * ll[i];
  }
  float invZ = 1.0f / Z;
  float* row = attn + (size_t)b * 2048;
#pragma unroll
  for (int i = 0; i < 8; ++i) {
    int s = t + 256 * i;
    row[s] = __expf(row[s] - M) * invZ;
  }
  if (t < 128) {
    float4 a = {0.f, 0.f, 0.f, 0.f};
#pragma unroll
    for (int c2 = 0; c2 < 32; ++c2) {
      float wv = wgt[c2];
      float4 p = *(const float4*)&psum[((size_t)(b * 32 + c2)) * 512 + (size_t)t * 4];
      a.x = fmaf(wv, p.x, a.x);
      a.y = fmaf(wv, p.y, a.y);
      a.z = fmaf(wv, p.z, a.z);
      a.w = fmaf(wv, p.w, a.w);
    }
    float4 r = {a.x * invZ, a.y * invZ, a.z * invZ, a.w * invZ};
    *(float4*)&out0[(size_t)b * 512 + (size_t)t * 4] = r;
  }
}

// ---------------------------------------------------------------------------
extern "C" void kernel_launch(void* const* d_in, const int* in_sizes, int n_in,
                              void* d_out, int out_size, void* d_ws, size_t ws_size,
                              hipStream_t stream) {
  (void)in_sizes; (void)n_in; (void)out_size; (void)ws_size;
  const float* enc  = (const float*)d_in[0];  // [64,2048,512] fp32
  const int*   msk  = (const int*)d_in[1];    // [64,2048] bool->int32
  const float* W    = (const float*)d_in[2];  // [512,512] fp32
  const float* bias = (const float*)d_in[3];  // [512] fp32
  const float* ctx  = (const float*)d_in[4];  // [512] fp32
  float* out0 = (float*)d_out;                // [64,512] weighted output
  float* attn = out0 + 64 * 512;              // [64,2048] scores -> attn (in place)

  __half* Wws  = (__half*)d_ws;                               // 512 KB
  float*  psum = (float*)((char*)d_ws + (512u << 10));        // 4 MB  [2048][512]
  float*  mprt = psum + (size_t)2048 * 512;                   // 8 KB
  float*  lprt = mprt + 2048;                                 // 8 KB

  k0_cvt_w<<<128, 256, 0, stream>>>(W, Wws);
  k1_scores<<<2048, 512, 0, stream>>>(enc, msk, bias, ctx, Wws, attn,
                                      psum, mprt, lprt);
  k2_combine<<<64, 256, 0, stream>>>(attn, psum, mprt, lprt, out0);
}